// Round 3
// baseline (309.169 us; speedup 1.0000x reference)
//
#include <hip/hip_runtime.h>
#include <cstdint>
#include <cstddef>

typedef _Float16 f16;
typedef __attribute__((ext_vector_type(4))) _Float16 f16x4;
typedef __attribute__((ext_vector_type(8))) _Float16 f16x8;
typedef __attribute__((ext_vector_type(16))) float f32x16;

static constexpr int BB = 4;
static constexpr int SS = 2048;
static constexpr int EE = 1024;

static constexpr int BM = 256, BN = 128, BK = 32;

// async global->LDS, 16B per lane. LDS dest must be wave-uniform base + lane*16.
__device__ __forceinline__ void gload_lds16(const f16* g, f16* l) {
  __builtin_amdgcn_global_load_lds(
      (const __attribute__((address_space(1))) void*)g,
      (__attribute__((address_space(3))) void*)l, 16, 0, 0);
}

struct Frag {
  int lane, wave, wy, wx, l32, lh;
  __device__ Frag() {
    const int tid = threadIdx.x;
    lane = tid & 63; wave = tid >> 6;
    wy = wave >> 1; wx = wave & 1;        // 2x2 wave grid over 256x128 block
    l32 = lane & 31; lh = lane >> 5;
  }
};

// C[m,n] = sum_k A[m,k] * Bt[n,k] (row-major, contraction over fast dim).
// Block 256x128, 4 waves 2x2, per-wave 128x64 via 4x2 mfma_32x32x16 frags.
// LDS layout XOR-swizzled (chunk kc ^ (row&3)) -- swizzle applied on the
// GLOBAL gather side so global_load_lds's uniform-base+lane*16 rule holds;
// makes b128 frag reads bank-conflict-free.
__device__ __forceinline__ void gemm_core(
    const f16* __restrict__ A, const f16* __restrict__ Bt,
    int lda, int ldb, int kIters,
    f16* __restrict__ Ash, f16* __restrict__ Bsh,
    f32x16 acc[4][2], const Frag& fr)
{
  // A tile 256x32 = 1024 16B chunks (4/thread); B tile 128x32 = 512 (2/thread)
  const f16* gA[4]; f16* lA[4];
#pragma unroll
  for (int i = 0; i < 4; ++i) {
    const int c = fr.wave * 256 + i * 64 + fr.lane;
    const int row = c >> 2;
    const int kc = (c & 3) ^ (row & 3);         // XOR swizzle
    gA[i] = A + (size_t)row * lda + kc * 8;
    lA[i] = Ash + c * 8;
  }
  const f16* gB[2]; f16* lB[2];
#pragma unroll
  for (int i = 0; i < 2; ++i) {
    const int c = fr.wave * 128 + i * 64 + fr.lane;
    const int row = c >> 2;
    const int kc = (c & 3) ^ (row & 3);
    gB[i] = Bt + (size_t)row * ldb + kc * 8;
    lB[i] = Bsh + c * 8;
  }
  // fragment LDS offsets (f16 units); rm&3 == l32&3 so perm is lane-constant per ks
  int aoff[2], boff[2];
#pragma unroll
  for (int ks = 0; ks < 2; ++ks) {
    const int perm = ((ks * 2 + fr.lh) ^ (fr.l32 & 3)) * 8;
    aoff[ks] = (fr.wy * 128 + fr.l32) * 32 + perm;
    boff[ks] = (fr.wx * 64 + fr.l32) * 32 + perm;
  }

  for (int kt = 0; kt < kIters; ++kt) {
    const int ko = kt * BK;
#pragma unroll
    for (int i = 0; i < 4; ++i) gload_lds16(gA[i] + ko, lA[i]);
#pragma unroll
    for (int i = 0; i < 2; ++i) gload_lds16(gB[i] + ko, lB[i]);
    __syncthreads();
#pragma unroll
    for (int ks = 0; ks < 2; ++ks) {
      f16x8 af[4], bf[2];
#pragma unroll
      for (int mi = 0; mi < 4; ++mi)
        af[mi] = *(const f16x8*)(Ash + aoff[ks] + mi * 32 * 32);
#pragma unroll
      for (int ni = 0; ni < 2; ++ni)
        bf[ni] = *(const f16x8*)(Bsh + boff[ks] + ni * 32 * 32);
#pragma unroll
      for (int mi = 0; mi < 4; ++mi)
#pragma unroll
        for (int ni = 0; ni < 2; ++ni)
          acc[mi][ni] = __builtin_amdgcn_mfma_f32_32x32x16_f16(af[mi], bf[ni], acc[mi][ni], 0, 0, 0);
    }
    __syncthreads();
  }
}

// ---------------- cast fp32 -> f16 ----------------
__global__ __launch_bounds__(256) void cast_kernel(
    const float* __restrict__ in, f16* __restrict__ out, int n4)
{
  const int i = blockIdx.x * 256 + threadIdx.x;
  if (i < n4) {
    const float4 f = ((const float4*)in)[i];
    f16x4 h;
    h.x = (f16)f.x; h.y = (f16)f.y; h.z = (f16)f.z; h.w = (f16)f.w;
    ((f16x4*)out)[i] = h;
  }
}

__global__ __launch_bounds__(256) void cast_w_kernel(
    const float* __restrict__ w0, const float* __restrict__ w1, const float* __restrict__ w2,
    f16* __restrict__ o0, f16* __restrict__ o1, f16* __restrict__ o2, int n4)
{
  const int z = blockIdx.y;
  const float* in = (z == 0) ? w0 : (z == 1) ? w1 : w2;
  f16* out = (z == 0) ? o0 : (z == 1) ? o1 : o2;
  const int i = blockIdx.x * 256 + threadIdx.x;
  if (i < n4) {
    const float4 f = ((const float4*)in)[i];
    f16x4 h;
    h.x = (f16)f.x; h.y = (f16)f.y; h.z = (f16)f.z; h.w = (f16)f.w;
    ((f16x4*)out)[i] = h;
  }
}

// ---------------- QKV projection: C = X @ W^T + b ----------------
__global__ __launch_bounds__(256, 2) void qkv_kernel(
    const f16* __restrict__ X,
    const f16* __restrict__ W0, const f16* __restrict__ W1, const f16* __restrict__ W2,
    const float* __restrict__ b0, const float* __restrict__ b1, const float* __restrict__ b2,
    f16* __restrict__ O0, f16* __restrict__ O1, f16* __restrict__ O2)
{
  __shared__ __align__(16) f16 Ash[BM * BK];
  __shared__ __align__(16) f16 Bsh[BN * BK];
  const int z = blockIdx.z;
  const f16* W = (z == 0) ? W0 : (z == 1) ? W1 : W2;
  const float* bias = (z == 0) ? b0 : (z == 1) ? b1 : b2;
  f16* out = (z == 0) ? O0 : (z == 1) ? O1 : O2;
  const int row0 = blockIdx.x * BM, col0 = blockIdx.y * BN;
  Frag fr;
  f32x16 acc[4][2] = {};
  gemm_core(X + (size_t)row0 * EE, W + (size_t)col0 * EE, EE, EE, EE / BK, Ash, Bsh, acc, fr);
#pragma unroll
  for (int ni = 0; ni < 2; ++ni) {
    const int c = col0 + fr.wx * 64 + ni * 32 + fr.l32;
    const float bv = bias[c];
#pragma unroll
    for (int mi = 0; mi < 4; ++mi) {
      const int rbase = row0 + fr.wy * 128 + mi * 32 + fr.lh * 4;
#pragma unroll
      for (int i = 0; i < 16; ++i) {
        const int r = rbase + (i & 3) + 8 * (i >> 2);
        out[(size_t)r * EE + c] = (f16)(acc[mi][ni][i] + bv);
      }
    }
  }
}

// ---------------- V transpose: Vt[e][s] = V[s][e] (per batch) ----------------
__global__ __launch_bounds__(256) void transpose_kernel(
    const f16* __restrict__ V, f16* __restrict__ Vt)
{
  __shared__ __align__(16) f16 t[64][68];
  const int b = blockIdx.z;
  const int s0 = blockIdx.x * 64, e0 = blockIdx.y * 64;
  const int tid = threadIdx.x;
  const int r = tid >> 4;
  const int c4 = (tid & 15) << 2;
  const f16* src = V + (size_t)b * SS * EE;
  f16* dst = Vt + (size_t)b * EE * SS;
#pragma unroll
  for (int i = 0; i < 4; ++i) {
    const int row = i * 16 + r;
    const f16x4 v = *(const f16x4*)(src + (size_t)(s0 + row) * EE + e0 + c4);
    *(f16x4*)&t[row][c4] = v;
  }
  __syncthreads();
#pragma unroll
  for (int i = 0; i < 4; ++i) {
    const int row = i * 16 + r;   // e-local
    f16x4 v;
    v.x = t[c4 + 0][row]; v.y = t[c4 + 1][row];
    v.z = t[c4 + 2][row]; v.w = t[c4 + 3][row];
    *(f16x4*)(dst + (size_t)(e0 + row) * SS + s0 + c4) = v;
  }
}

// ---------------- scores: Sc[q,k] = (Q[q,:] . K[k,:]) / 32 ----------------
// 256x128 tiles; grid.x enumerates tiles with kt*128 < (qt+1)*256 (72/batch).
// Values above the diagonal inside the band are written unmasked; softmax
// zero-fills them (kend = 256-boundary) before PV reads.
__global__ __launch_bounds__(256, 2) void scores_kernel(
    const f16* __restrict__ Q, const f16* __restrict__ Kh, f16* __restrict__ Sc)
{
  __shared__ __align__(16) f16 Ash[BM * BK];
  __shared__ __align__(16) f16 Bsh[BN * BK];
  const int t = blockIdx.x, b = blockIdx.z;
  int qt = 0;
  while ((qt + 1) * (qt + 2) <= t) ++qt;      // cum(qt) = qt*(qt+1); kt in [0, 2qt+2)
  const int kt = t - qt * (qt + 1);
  const f16* A  = Q  + (size_t)b * SS * EE + (size_t)qt * BM * EE;
  const f16* Bp = Kh + (size_t)b * SS * EE + (size_t)kt * BN * EE;
  f16* out = Sc + (size_t)b * SS * SS;
  Frag fr;
  f32x16 acc[4][2] = {};
  gemm_core(A, Bp, EE, EE, EE / BK, Ash, Bsh, acc, fr);
  const float scale = 0.03125f;   // 1/sqrt(1024)
#pragma unroll
  for (int ni = 0; ni < 2; ++ni) {
    const int c = kt * BN + fr.wx * 64 + ni * 32 + fr.l32;
#pragma unroll
    for (int mi = 0; mi < 4; ++mi) {
      const int rbase = qt * BM + fr.wy * 128 + mi * 32 + fr.lh * 4;
#pragma unroll
      for (int i = 0; i < 16; ++i) {
        const int r = rbase + (i & 3) + 8 * (i >> 2);
        out[(size_t)r * SS + c] = (f16)(acc[mi][ni][i] * scale);
      }
    }
  }
}

// ---------------- in-place causal softmax over row q (vectorized f16x8) ----------------
// zero-fills (n, kend) where kend = next 256 boundary (PV reads 256-col tiles)
__global__ __launch_bounds__(256) void softmax_kernel(f16* __restrict__ Sc)
{
  const int q = blockIdx.x, b = blockIdx.y;
  f16* row = Sc + (size_t)b * SS * SS + (size_t)q * SS;
  const int n = q + 1;
  const int kend = ((q >> 8) + 1) << 8;   // PV q-band reads K up to this boundary
  const int tid = threadIdx.x;
  const int i0 = tid * 8;

  float v[8];
  if (i0 + 8 <= n) {
    const f16x8 h = *(const f16x8*)(row + i0);
#pragma unroll
    for (int j = 0; j < 8; ++j) v[j] = (float)h[j];
  } else {
#pragma unroll
    for (int j = 0; j < 8; ++j) {
      const int idx = i0 + j;
      v[j] = (idx < n) ? (float)row[idx] : -1e30f;
    }
  }

  float m = v[0];
#pragma unroll
  for (int j = 1; j < 8; ++j) m = fmaxf(m, v[j]);
  __shared__ float red[4];
#pragma unroll
  for (int off = 32; off > 0; off >>= 1) m = fmaxf(m, __shfl_down(m, off));
  if ((tid & 63) == 0) red[tid >> 6] = m;
  __syncthreads();
  m = fmaxf(fmaxf(red[0], red[1]), fmaxf(red[2], red[3]));

  float sum = 0.f;
#pragma unroll
  for (int j = 0; j < 8; ++j) {
    v[j] = (i0 + j < n) ? __expf(v[j] - m) : 0.f;
    sum += v[j];
  }
#pragma unroll
  for (int off = 32; off > 0; off >>= 1) sum += __shfl_down(sum, off);
  __syncthreads();
  if ((tid & 63) == 0) red[tid >> 6] = sum;
  __syncthreads();
  sum = red[0] + red[1] + red[2] + red[3];
  const float inv = 1.f / sum;

  if (i0 < kend) {                         // kend is a multiple of 256 >= n
    f16x8 h;
#pragma unroll
    for (int j = 0; j < 8; ++j) h[j] = (f16)(v[j] * inv);   // v==0 beyond n
    *(f16x8*)(row + i0) = h;
  }
}

// ---------------- PV: Y[q,e] = sum_{k<=q} P[q,k] * Vt[e,k], fp32 out ----------------
// qt reversed so heaviest (longest-K) blocks dispatch first
__global__ __launch_bounds__(256, 2) void pv_kernel(
    const f16* __restrict__ P, const f16* __restrict__ Vt, float* __restrict__ Y)
{
  __shared__ __align__(16) f16 Ash[BM * BK];
  __shared__ __align__(16) f16 Bsh[BN * BK];
  const int qt = (gridDim.x - 1) - blockIdx.x, et = blockIdx.y, b = blockIdx.z;
  const f16* A  = P  + (size_t)b * SS * SS + (size_t)qt * BM * SS;
  const f16* Bp = Vt + (size_t)b * EE * SS + (size_t)et * BN * SS;
  float* out = Y + (size_t)b * SS * EE;
  Frag fr;
  f32x16 acc[4][2] = {};
  gemm_core(A, Bp, SS, SS, (qt + 1) * (BM / BK), Ash, Bsh, acc, fr);
#pragma unroll
  for (int ni = 0; ni < 2; ++ni) {
    const int c = et * BN + fr.wx * 64 + ni * 32 + fr.l32;
#pragma unroll
    for (int mi = 0; mi < 4; ++mi) {
      const int rbase = qt * BM + fr.wy * 128 + mi * 32 + fr.lh * 4;
#pragma unroll
      for (int i = 0; i < 16; ++i) {
        const int r = rbase + (i & 3) + 8 * (i >> 2);
        out[(size_t)r * EE + c] = acc[mi][ni][i];
      }
    }
  }
}

extern "C" void kernel_launch(void* const* d_in, const int* in_sizes, int n_in,
                              void* d_out, int out_size, void* d_ws, size_t ws_size,
                              hipStream_t stream)
{
  const float* xs  = (const float*)d_in[0];
  const float* WQw = (const float*)d_in[1];
  const float* WQb = (const float*)d_in[2];
  const float* WKw = (const float*)d_in[3];
  const float* WKb = (const float*)d_in[4];
  const float* WVw = (const float*)d_in[5];
  const float* WVb = (const float*)d_in[6];

  const size_t ME = (size_t)BB * SS * EE;   // 8M tokens*dim
  const size_t WE = (size_t)EE * EE;        // 1M weight elems

  f16* Xh = (f16*)d_ws;
  f16* Wq = Xh + ME;
  f16* Wk = Wq + WE;
  f16* Wv = Wk + WE;
  f16* Qh = Wv + WE;
  f16* Kh = Qh + ME;
  f16* Vh = Kh + ME;
  f16* Vt = Vh + ME;
  f16* Sc = Vt + ME;   // BB*SS*SS f16 = 32 MiB

  cast_kernel<<<dim3((unsigned)(ME / 4 / 256)), 256, 0, stream>>>(xs, Xh, (int)(ME / 4));
  cast_w_kernel<<<dim3((unsigned)(WE / 4 / 256), 3), 256, 0, stream>>>(
      WQw, WKw, WVw, Wq, Wk, Wv, (int)(WE / 4));

  qkv_kernel<<<dim3((BB * SS) / BM, EE / BN, 3), 256, 0, stream>>>(
      Xh, Wq, Wk, Wv, WQb, WKb, WVb, Qh, Kh, Vh);
  transpose_kernel<<<dim3(SS / 64, EE / 64, BB), 256, 0, stream>>>(Vh, Vt);
  const int nQT = SS / BM;                       // 8
  const int nTri = nQT * (nQT + 1);              // 72 tiles (kt range 2qt+2)
  scores_kernel<<<dim3(nTri, 1, BB), 256, 0, stream>>>(Qh, Kh, Sc);
  softmax_kernel<<<dim3(SS, BB), 256, 0, stream>>>(Sc);
  pv_kernel<<<dim3(SS / BM, EE / BN, BB), 256, 0, stream>>>(Sc, Vt, (float*)d_out);
}

// Round 4
// 265.328 us; speedup vs baseline: 1.1652x; 1.1652x over previous
//
#include <hip/hip_runtime.h>
#include <cstdint>
#include <cstddef>

typedef _Float16 f16;
typedef __attribute__((ext_vector_type(4))) _Float16 f16x4;
typedef __attribute__((ext_vector_type(8))) _Float16 f16x8;
typedef __attribute__((ext_vector_type(4))) float f32x4;

static constexpr int BB = 4;
static constexpr int SS = 2048;
static constexpr int EE = 1024;

static constexpr int BM = 128, BN = 128, BK = 32;

// async global->LDS, 16B per lane. LDS dest must be wave-uniform base + lane*16.
__device__ __forceinline__ void gload_lds16(const f16* g, f16* l) {
  __builtin_amdgcn_global_load_lds(
      (const __attribute__((address_space(1))) void*)g,
      (__attribute__((address_space(3))) void*)l, 16, 0, 0);
}

struct Frag {
  int lane, wave, wy, wx, l16, quad;
  __device__ Frag() {
    const int tid = threadIdx.x;
    lane = tid & 63; wave = tid >> 6;
    wy = wave >> 1; wx = wave & 1;
    l16 = lane & 15; quad = lane >> 4;
  }
};

// C[m,n] = sum_k A[m,k] * Bt[n,k]   (both row-major, contraction over fast dim)
// 128x128 tile, 256 threads (4 waves, 2x2 wave grid, 4x4 16x16 MFMA frags/wave)
__device__ __forceinline__ void gemm_core(
    const f16* __restrict__ A, const f16* __restrict__ Bt,
    int lda, int ldb, int kTiles,
    f16* __restrict__ Ash, f16* __restrict__ Bsh,
    f32x4 acc[4][4], const Frag& fr)
{
  const int ca0 = fr.wave * 128 + fr.lane;
  const int ca1 = ca0 + 64;
  const int ra0 = ca0 >> 2, ka0 = (ca0 & 3) << 3;
  const int ra1 = ca1 >> 2, ka1 = (ca1 & 3) << 3;

  const f16* gA0 = A + (size_t)ra0 * lda + ka0;
  const f16* gA1 = A + (size_t)ra1 * lda + ka1;
  const f16* gB0 = Bt + (size_t)ra0 * ldb + ka0;
  const f16* gB1 = Bt + (size_t)ra1 * ldb + ka1;
  f16* lA0 = Ash + ca0 * 8;
  f16* lA1 = Ash + ca1 * 8;
  f16* lB0 = Bsh + ca0 * 8;
  f16* lB1 = Bsh + ca1 * 8;

  for (int kt = 0; kt < kTiles; ++kt) {
    const int ko = kt * BK;
    gload_lds16(gA0 + ko, lA0);
    gload_lds16(gA1 + ko, lA1);
    gload_lds16(gB0 + ko, lB0);
    gload_lds16(gB1 + ko, lB1);
    __syncthreads();
    f16x8 af[4], bf[4];
#pragma unroll
    for (int mi = 0; mi < 4; ++mi)
      af[mi] = *(const f16x8*)(Ash + (fr.wy * 64 + mi * 16 + fr.l16) * BK + fr.quad * 8);
#pragma unroll
    for (int ni = 0; ni < 4; ++ni)
      bf[ni] = *(const f16x8*)(Bsh + (fr.wx * 64 + ni * 16 + fr.l16) * BK + fr.quad * 8);
#pragma unroll
    for (int mi = 0; mi < 4; ++mi)
#pragma unroll
      for (int ni = 0; ni < 4; ++ni)
        acc[mi][ni] = __builtin_amdgcn_mfma_f32_16x16x32_f16(af[mi], bf[ni], acc[mi][ni], 0, 0, 0);
    __syncthreads();
  }
}

// ---------------- cast fp32 -> f16 ----------------
__global__ __launch_bounds__(256) void cast_kernel(
    const float* __restrict__ in, f16* __restrict__ out, int n4)
{
  const int i = blockIdx.x * 256 + threadIdx.x;
  if (i < n4) {
    const float4 f = ((const float4*)in)[i];
    f16x4 h;
    h.x = (f16)f.x; h.y = (f16)f.y; h.z = (f16)f.z; h.w = (f16)f.w;
    ((f16x4*)out)[i] = h;
  }
}

__global__ __launch_bounds__(256) void cast_w_kernel(
    const float* __restrict__ w0, const float* __restrict__ w1, const float* __restrict__ w2,
    f16* __restrict__ o0, f16* __restrict__ o1, f16* __restrict__ o2, int n4)
{
  const int z = blockIdx.y;
  const float* in = (z == 0) ? w0 : (z == 1) ? w1 : w2;
  f16* out = (z == 0) ? o0 : (z == 1) ? o1 : o2;
  const int i = blockIdx.x * 256 + threadIdx.x;
  if (i < n4) {
    const float4 f = ((const float4*)in)[i];
    f16x4 h;
    h.x = (f16)f.x; h.y = (f16)f.y; h.z = (f16)f.z; h.w = (f16)f.w;
    ((f16x4*)out)[i] = h;
  }
}

// ---------------- fused QKV: one A-staging feeds 3 weight GEMMs ----------------
// Per K-iter: stage A(8KB) + Wq/Wk/Wv tiles(24KB), 48 MFMA per barrier (3x m97's
// MFMA density per drain). Grid 64x8 = 512 blocks = exactly 2/CU.
__global__ __launch_bounds__(256, 2) void qkv_fused_kernel(
    const f16* __restrict__ X,
    const f16* __restrict__ W0, const f16* __restrict__ W1, const f16* __restrict__ W2,
    const float* __restrict__ b0, const float* __restrict__ b1, const float* __restrict__ b2,
    f16* __restrict__ O0, f16* __restrict__ O1, f16* __restrict__ O2)
{
  __shared__ __align__(16) f16 Ash[BM * BK];
  __shared__ __align__(16) f16 Bsh[3][BN * BK];
  const int row0 = blockIdx.x * BM, col0 = blockIdx.y * BN;
  Frag fr;

  const int ca0 = fr.wave * 128 + fr.lane;
  const int ca1 = ca0 + 64;
  const int ra0 = ca0 >> 2, ka0 = (ca0 & 3) << 3;
  const int ra1 = ca1 >> 2, ka1 = (ca1 & 3) << 3;

  const f16* gA0 = X + (size_t)(row0 + ra0) * EE + ka0;
  const f16* gA1 = X + (size_t)(row0 + ra1) * EE + ka1;
  const f16* gW[3][2];
  gW[0][0] = W0 + (size_t)(col0 + ra0) * EE + ka0;
  gW[0][1] = W0 + (size_t)(col0 + ra1) * EE + ka1;
  gW[1][0] = W1 + (size_t)(col0 + ra0) * EE + ka0;
  gW[1][1] = W1 + (size_t)(col0 + ra1) * EE + ka1;
  gW[2][0] = W2 + (size_t)(col0 + ra0) * EE + ka0;
  gW[2][1] = W2 + (size_t)(col0 + ra1) * EE + ka1;
  f16* lA0 = Ash + ca0 * 8;
  f16* lA1 = Ash + ca1 * 8;

  f32x4 acc[3][4][4] = {};

  for (int kt = 0; kt < EE / BK; ++kt) {
    const int ko = kt * BK;
    gload_lds16(gA0 + ko, lA0);
    gload_lds16(gA1 + ko, lA1);
#pragma unroll
    for (int z = 0; z < 3; ++z) {
      gload_lds16(gW[z][0] + ko, Bsh[z] + ca0 * 8);
      gload_lds16(gW[z][1] + ko, Bsh[z] + ca1 * 8);
    }
    __syncthreads();
    f16x8 af[4];
#pragma unroll
    for (int mi = 0; mi < 4; ++mi)
      af[mi] = *(const f16x8*)(Ash + (fr.wy * 64 + mi * 16 + fr.l16) * BK + fr.quad * 8);
#pragma unroll
    for (int z = 0; z < 3; ++z) {
      f16x8 bf[4];
#pragma unroll
      for (int ni = 0; ni < 4; ++ni)
        bf[ni] = *(const f16x8*)(Bsh[z] + (fr.wx * 64 + ni * 16 + fr.l16) * BK + fr.quad * 8);
#pragma unroll
      for (int mi = 0; mi < 4; ++mi)
#pragma unroll
        for (int ni = 0; ni < 4; ++ni)
          acc[z][mi][ni] = __builtin_amdgcn_mfma_f32_16x16x32_f16(af[mi], bf[ni], acc[z][mi][ni], 0, 0, 0);
    }
    __syncthreads();
  }

#pragma unroll
  for (int z = 0; z < 3; ++z) {
    const float* bias = (z == 0) ? b0 : (z == 1) ? b1 : b2;
    f16* out = (z == 0) ? O0 : (z == 1) ? O1 : O2;
#pragma unroll
    for (int ni = 0; ni < 4; ++ni) {
      const int c = col0 + fr.wx * 64 + ni * 16 + fr.l16;
      const float bv = bias[c];
#pragma unroll
      for (int mi = 0; mi < 4; ++mi) {
        const int r = row0 + fr.wy * 64 + mi * 16 + fr.quad * 4;
#pragma unroll
        for (int i = 0; i < 4; ++i)
          out[(size_t)(r + i) * EE + c] = (f16)(acc[z][mi][ni][i] + bv);
      }
    }
  }
}

// ---------------- V transpose: Vt[e][s] = V[s][e] (per batch) ----------------
__global__ __launch_bounds__(256) void transpose_kernel(
    const f16* __restrict__ V, f16* __restrict__ Vt)
{
  __shared__ __align__(16) f16 t[64][68];
  const int b = blockIdx.z;
  const int s0 = blockIdx.x * 64, e0 = blockIdx.y * 64;
  const int tid = threadIdx.x;
  const int r = tid >> 4;
  const int c4 = (tid & 15) << 2;
  const f16* src = V + (size_t)b * SS * EE;
  f16* dst = Vt + (size_t)b * EE * SS;
#pragma unroll
  for (int i = 0; i < 4; ++i) {
    const int row = i * 16 + r;
    const f16x4 v = *(const f16x4*)(src + (size_t)(s0 + row) * EE + e0 + c4);
    *(f16x4*)&t[row][c4] = v;
  }
  __syncthreads();
#pragma unroll
  for (int i = 0; i < 4; ++i) {
    const int row = i * 16 + r;   // e-local
    f16x4 v;
    v.x = t[c4 + 0][row]; v.y = t[c4 + 1][row];
    v.z = t[c4 + 2][row]; v.w = t[c4 + 3][row];
    *(f16x4*)(dst + (size_t)(e0 + row) * SS + s0 + c4) = v;
  }
}

// ---------------- scores: Sc[q,k] = (Q[q,:] . K[k,:]) / 32, lower-tri tiles only ----------------
__global__ __launch_bounds__(256) void scores_kernel(
    const f16* __restrict__ Q, const f16* __restrict__ Kh, f16* __restrict__ Sc)
{
  __shared__ __align__(16) f16 Ash[BM * BK];
  __shared__ __align__(16) f16 Bsh[BN * BK];
  const int t = blockIdx.x, b = blockIdx.z;
  int qt = 0;
  while ((qt + 1) * (qt + 2) / 2 <= t) ++qt;
  const int kt = t - qt * (qt + 1) / 2;
  const f16* A  = Q  + (size_t)b * SS * EE + (size_t)qt * BM * EE;
  const f16* Bp = Kh + (size_t)b * SS * EE + (size_t)kt * BN * EE;
  f16* out = Sc + (size_t)b * SS * SS;
  Frag fr;
  f32x4 acc[4][4] = {};
  gemm_core(A, Bp, EE, EE, EE / BK, Ash, Bsh, acc, fr);
  const float scale = 0.03125f;   // 1/sqrt(1024)
#pragma unroll
  for (int ni = 0; ni < 4; ++ni) {
    const int c = kt * BN + fr.wx * 64 + ni * 16 + fr.l16;
#pragma unroll
    for (int mi = 0; mi < 4; ++mi) {
      const int r = qt * BM + fr.wy * 64 + mi * 16 + fr.quad * 4;
#pragma unroll
      for (int i = 0; i < 4; ++i)
        out[(size_t)(r + i) * SS + c] = (f16)(acc[mi][ni][i] * scale);
    }
  }
}

// ---------------- in-place causal softmax over row q (vectorized f16x8) ----------------
__global__ __launch_bounds__(256) void softmax_kernel(f16* __restrict__ Sc)
{
  const int q = blockIdx.x, b = blockIdx.y;
  f16* row = Sc + (size_t)b * SS * SS + (size_t)q * SS;
  const int n = q + 1;
  const int kend = ((q >> 7) + 1) << 7;   // diagonal-tile edge
  const int tid = threadIdx.x;
  const int i0 = tid * 8;

  float v[8];
  if (i0 + 8 <= n) {
    const f16x8 h = *(const f16x8*)(row + i0);
#pragma unroll
    for (int j = 0; j < 8; ++j) v[j] = (float)h[j];
  } else {
#pragma unroll
    for (int j = 0; j < 8; ++j) {
      const int idx = i0 + j;
      v[j] = (idx < n) ? (float)row[idx] : -1e30f;
    }
  }

  float m = v[0];
#pragma unroll
  for (int j = 1; j < 8; ++j) m = fmaxf(m, v[j]);
  __shared__ float red[4];
#pragma unroll
  for (int off = 32; off > 0; off >>= 1) m = fmaxf(m, __shfl_down(m, off));
  if ((tid & 63) == 0) red[tid >> 6] = m;
  __syncthreads();
  m = fmaxf(fmaxf(red[0], red[1]), fmaxf(red[2], red[3]));

  float sum = 0.f;
#pragma unroll
  for (int j = 0; j < 8; ++j) {
    v[j] = (i0 + j < n) ? __expf(v[j] - m) : 0.f;
    sum += v[j];
  }
#pragma unroll
  for (int off = 32; off > 0; off >>= 1) sum += __shfl_down(sum, off);
  __syncthreads();
  if ((tid & 63) == 0) red[tid >> 6] = sum;
  __syncthreads();
  sum = red[0] + red[1] + red[2] + red[3];
  const float inv = 1.f / sum;

  if (i0 < kend) {
    f16x8 h;
#pragma unroll
    for (int j = 0; j < 8; ++j) h[j] = (f16)(v[j] * inv);   // v==0 beyond n
    *(f16x8*)(row + i0) = h;
  }
}

// ---------------- PV: Y[q,e] = sum_{k<=q} P[q,k] * Vt[e,k], fp32 out ----------------
__global__ __launch_bounds__(256) void pv_kernel(
    const f16* __restrict__ P, const f16* __restrict__ Vt, float* __restrict__ Y)
{
  __shared__ __align__(16) f16 Ash[BM * BK];
  __shared__ __align__(16) f16 Bsh[BN * BK];
  const int qt = (gridDim.x - 1) - blockIdx.x, et = blockIdx.y, b = blockIdx.z;
  const f16* A  = P  + (size_t)b * SS * SS + (size_t)qt * BM * SS;
  const f16* Bp = Vt + (size_t)b * EE * SS + (size_t)et * BN * SS;
  float* out = Y + (size_t)b * SS * EE;
  Frag fr;
  f32x4 acc[4][4] = {};
  gemm_core(A, Bp, SS, SS, (qt + 1) * (BM / BK), Ash, Bsh, acc, fr);
#pragma unroll
  for (int ni = 0; ni < 4; ++ni) {
    const int c = et * BN + fr.wx * 64 + ni * 16 + fr.l16;
#pragma unroll
    for (int mi = 0; mi < 4; ++mi) {
      const int r = qt * BM + fr.wy * 64 + mi * 16 + fr.quad * 4;
#pragma unroll
      for (int i = 0; i < 4; ++i)
        out[(size_t)(r + i) * EE + c] = acc[mi][ni][i];
    }
  }
}

extern "C" void kernel_launch(void* const* d_in, const int* in_sizes, int n_in,
                              void* d_out, int out_size, void* d_ws, size_t ws_size,
                              hipStream_t stream)
{
  const float* xs  = (const float*)d_in[0];
  const float* WQw = (const float*)d_in[1];
  const float* WQb = (const float*)d_in[2];
  const float* WKw = (const float*)d_in[3];
  const float* WKb = (const float*)d_in[4];
  const float* WVw = (const float*)d_in[5];
  const float* WVb = (const float*)d_in[6];

  const size_t ME = (size_t)BB * SS * EE;   // 8M tokens*dim
  const size_t WE = (size_t)EE * EE;        // 1M weight elems

  f16* Xh = (f16*)d_ws;
  f16* Wq = Xh + ME;
  f16* Wk = Wq + WE;
  f16* Wv = Wk + WE;
  f16* Qh = Wv + WE;
  f16* Kh = Qh + ME;
  f16* Vh = Kh + ME;
  f16* Vt = Vh + ME;
  f16* Sc = Vt + ME;   // BB*SS*SS f16 = 32 MiB

  cast_kernel<<<dim3((unsigned)(ME / 4 / 256)), 256, 0, stream>>>(xs, Xh, (int)(ME / 4));
  cast_w_kernel<<<dim3((unsigned)(WE / 4 / 256), 3), 256, 0, stream>>>(
      WQw, WKw, WVw, Wq, Wk, Wv, (int)(WE / 4));

  qkv_fused_kernel<<<dim3((BB * SS) / BM, EE / BN), 256, 0, stream>>>(
      Xh, Wq, Wk, Wv, WQb, WKb, WVb, Qh, Kh, Vh);
  transpose_kernel<<<dim3(SS / 64, EE / 64, BB), 256, 0, stream>>>(Vh, Vt);
  const int nTri = (SS / BM) * (SS / BM + 1) / 2;   // 136
  scores_kernel<<<dim3(nTri, 1, BB), 256, 0, stream>>>(Qh, Kh, Sc);
  softmax_kernel<<<dim3(SS, BB), 256, 0, stream>>>(Sc);
  pv_kernel<<<dim3(SS / BM, EE / BN, BB), 256, 0, stream>>>(Sc, Vt, (float*)d_out);
}